// Round 4
// baseline (102.590 us; speedup 1.0000x reference)
//
#include <hip/hip_runtime.h>

#define W_IN  4096
#define H_IN  4096
#define W_OUT 4090
#define H_OUT 4090
#define STRIP 16            // output rows per wave
#define NIN   (STRIP + 6)   // 22 input rows streamed per wave
#define RING  8             // LDS ring slots (power of 2 for static &7)
#define SLOTW 264           // floats per slot: 262 needed, padded to 16B mult

__device__ __forceinline__ void gl_lds16(const float* g, float* l) {
    // stages 16B per lane: LDS dest = uniform base + lane*16 (linear)
    __builtin_amdgcn_global_load_lds(
        (const __attribute__((address_space(1))) void*)g,
        (__attribute__((address_space(3))) void*)l,
        16, 0, 0);
}

__global__ __launch_bounds__(256, 4) void conv7x7(
    const float* __restrict__ x, const float* __restrict__ wgt,
    const float* __restrict__ bias, float* __restrict__ out)
{
    __shared__ float lds[4][RING][SLOTW];   // 33,792 B -> 4 blocks/CU

    const int lane = threadIdx.x & 63;
    const int wid  = threadIdx.x >> 6;
    const int x0   = blockIdx.x * 256;              // 16 tiles cover 4096 exactly
    const int ry0  = blockIdx.y * 64 + wid * STRIP; // wave-private strip
    const bool halo = (x0 + (SLOTW)) <= W_IN;       // x-tiles 0..14 stage 6-col halo

    // weights + bias: uniform addresses -> SGPR-resident scalar loads
    float Wt[49];
    #pragma unroll
    for (int i = 0; i < 49; ++i) Wt[i] = wgt[i];
    const float bb = bias[0];

    float (*myl)[SLOTW] = lds[wid];
    const int cx = x0 + lane * 4;

    // stage input row (strip-local r) into ring slot r&7; y clamped (garbage
    // rows only ever feed outputs >= H_OUT, which are discarded)
    auto STAGE = [&](int r) {
        int gy = ry0 + r;
        gy = gy < H_IN ? gy : (H_IN - 1);
        const float* src = x + (size_t)gy * W_IN + x0;
        gl_lds16(src + lane * 4, &myl[r & 7][0]);       // cols 0..255 (1024B)
        if (halo && lane < 2)
            gl_lds16(src + 256 + lane * 4, &myl[r & 7][256]); // cols 256..263
    };

    #pragma unroll
    for (int r = 0; r < 7; ++r) STAGE(r);   // prologue: rows 0..6 in flight

    float acc[7][4];
    #pragma unroll
    for (int s = 0; s < 7; ++s)
        #pragma unroll
        for (int c = 0; c < 4; ++c) acc[s][c] = 0.f;

    #pragma unroll
    for (int r = 0; r < NIN; ++r) {
        // row r's stage is >= 1 full iteration old (issued below, last iter);
        // drain before reading its slot. Per-wave wait: other waves keep running.
        asm volatile("s_waitcnt vmcnt(0)" ::: "memory");

        const float* lrow = &myl[r & 7][lane * 4];
        const float4 p0 = *reinterpret_cast<const float4*>(lrow);
        const float4 p1 = *reinterpret_cast<const float4*>(lrow + 4);
        const float2 p2 = *reinterpret_cast<const float2*>(lrow + 8);
        const float f[10] = {p0.x, p0.y, p0.z, p0.w,
                             p1.x, p1.y, p1.z, p1.w, p2.x, p2.y};

        // prefetch: slot (r+7)&7 == (r-1)&7, consumed last iteration
        if (r + 7 < NIN) STAGE(r + 7);

        // accumulate row r into every output row it touches (all-static ring)
        #pragma unroll
        for (int ky = 0; ky < 7; ++ky) {
            const int oy = r - ky;                 // static
            if (oy >= 0 && oy < STRIP) {           // static predicate
                #pragma unroll
                for (int kx = 0; kx < 7; ++kx) {
                    const float w = Wt[ky * 7 + kx];
                    acc[oy % 7][0] += w * f[kx + 0];
                    acc[oy % 7][1] += w * f[kx + 1];
                    acc[oy % 7][2] += w * f[kx + 2];
                    acc[oy % 7][3] += w * f[kx + 3];
                }
            }
        }

        // input row r completes output row r-6
        const int oy = r - 6;                      // static
        if (oy >= 0) {                             // oy <= 15 always (r <= 21)
            const int s = oy % 7;                  // static
            const int gyo = ry0 + oy;
            if (gyo < H_OUT) {
                float* po = out + (size_t)gyo * W_OUT + cx;
                if (cx + 4 <= W_OUT) {             // cx even -> 8B-aligned
                    *reinterpret_cast<float2*>(po) =
                        make_float2(acc[s][0] + bb, acc[s][1] + bb);
                    *reinterpret_cast<float2*>(po + 2) =
                        make_float2(acc[s][2] + bb, acc[s][3] + bb);
                } else {
                    #pragma unroll
                    for (int c = 0; c < 4; ++c)
                        if (cx + c < W_OUT) po[c] = acc[s][c] + bb;
                }
            }
            #pragma unroll
            for (int c = 0; c < 4; ++c) acc[s][c] = 0.f;
        }
    }
}

extern "C" void kernel_launch(void* const* d_in, const int* in_sizes, int n_in,
                              void* d_out, int out_size, void* d_ws, size_t ws_size,
                              hipStream_t stream) {
    const float* x = (const float*)d_in[0];
    const float* w = (const float*)d_in[1];
    const float* b = (const float*)d_in[2];
    float* out = (float*)d_out;
    // x: 4096/256 = 16 tiles; y: 64 blocks x 64 rows = 4096 >= 4090
    dim3 grid(16, 64);
    conv7x7<<<grid, 256, 0, stream>>>(x, w, b, out);
}